// Round 6
// baseline (99.677 us; speedup 1.0000x reference)
//
#include <hip/hip_runtime.h>

// LIF spike recurrence:
//   u_t = u_{t-1} - Vth * o_{t-1} + x_t ;  o_t = (u_t > Vth) ? 1 : 0
// x: [T=16, N=4194304] float32, out: same shape float32.
//
// Round-6 structure: each thread owns FOUR independent spatial float4 chunks
// (grid-strided, coalesced). The 4 recurrence chains are independent, so each
// timestep issues 4 independent global_load_dwordx4 — structural MLP the
// register allocator cannot serialize away (rounds 3-5: asm/sched tricks to
// force a 16-deep pipeline were all undone, VGPR stuck at 36). Nontemporal
// stores keep WRITE_SIZE at the compulsory 268 MB and preserve x in L3
// (FETCH ~131 MB, half L3-served).

#define LIF_VTH   1.0f
#define LIF_STEPS 16
#define CHUNKS    4

typedef float fx4 __attribute__((ext_vector_type(4)));

__global__ __launch_bounds__(256) void LIFSpike_84542136254876_kernel(
    const fx4* __restrict__ x, fx4* __restrict__ out, int n4) {
    int tid    = blockIdx.x * blockDim.x + threadIdx.x;
    int stride = gridDim.x * blockDim.x;

    fx4 u[CHUNKS], o[CHUNKS];
#pragma unroll
    for (int c = 0; c < CHUNKS; ++c) { u[c] = (fx4)0.0f; o[c] = (fx4)0.0f; }

#pragma unroll
    for (int t = 0; t < LIF_STEPS; ++t) {
        const size_t plane = (size_t)t * (size_t)n4;
        fx4 xt[CHUNKS];
        // 4 independent loads issued together (different chains).
#pragma unroll
        for (int c = 0; c < CHUNKS; ++c) {
            int idx = tid + c * stride;
            if (idx < n4) xt[c] = x[plane + (size_t)idx];
        }
#pragma unroll
        for (int c = 0; c < CHUNKS; ++c) {
            int idx = tid + c * stride;
            if (idx < n4) {
                u[c] = u[c] - o[c] + xt[c];
                fx4 on;
                on.x = (u[c].x > LIF_VTH) ? 1.0f : 0.0f;
                on.y = (u[c].y > LIF_VTH) ? 1.0f : 0.0f;
                on.z = (u[c].z > LIF_VTH) ? 1.0f : 0.0f;
                on.w = (u[c].w > LIF_VTH) ? 1.0f : 0.0f;
                o[c] = on;
                __builtin_nontemporal_store(o[c], &out[plane + (size_t)idx]);
            }
        }
    }
}

extern "C" void kernel_launch(void* const* d_in, const int* in_sizes, int n_in,
                              void* d_out, int out_size, void* d_ws, size_t ws_size,
                              hipStream_t stream) {
    const float* x = (const float*)d_in[0];
    float* out = (float*)d_out;

    int total = in_sizes[0];          // T * N
    int n = total / LIF_STEPS;        // spatial elements per timestep
    int n4 = n / 4;                   // float4 elements per timestep

    int block = 256;
    int grid = (n4 + block * CHUNKS - 1) / (block * CHUNKS);

    LIFSpike_84542136254876_kernel<<<grid, block, 0, stream>>>(
        (const fx4*)x, (fx4*)out, n4);
}

// Round 7
// 89.606 us; speedup vs baseline: 1.1124x; 1.1124x over previous
//
#include <hip/hip_runtime.h>

// LIF spike recurrence:
//   u_t = u_{t-1} - Vth * o_{t-1} + x_t ;  o_t = (u_t > Vth) ? 1 : 0
// x: [T=16, N=4194304] float32, out: same shape float32.
//
// Round-7 structure: one float4 per thread (full 4096-block grid = max TLP,
// round 6 showed trading TLP for MLP loses) + an explicit DEPTH-4 rotating
// load pipeline (buf[t&3], statically indexed under full unroll). Prologue
// issues loads t=0..3; each step consumes slot t, computes, nontemporal-
// stores, then issues load t+4 -> structurally 4 loads in flight per wave
// within a ~56-VGPR budget (stays under the 64-VGPR / 8-waves-per-SIMD
// occupancy cliff; rounds 3-5 showed 16-deep gets re-sunk by the RA).
// NT stores keep WRITE_SIZE at the compulsory 268 MB and x L3-resident.

#define LIF_VTH   1.0f
#define LIF_STEPS 16
#define DEPTH     4

typedef float fx4 __attribute__((ext_vector_type(4)));

__global__ __launch_bounds__(256) void LIFSpike_84542136254876_kernel(
    const fx4* __restrict__ x, fx4* __restrict__ out, int n4) {
    int i = blockIdx.x * blockDim.x + threadIdx.x;
    if (i >= n4) return;

    // Prologue: fill the 4-slot pipeline.
    fx4 buf[DEPTH];
#pragma unroll
    for (int t = 0; t < DEPTH; ++t) {
        buf[t] = x[(size_t)t * (size_t)n4 + (size_t)i];
    }

    fx4 u = (fx4)0.0f;
    fx4 o = (fx4)0.0f;
#pragma unroll
    for (int t = 0; t < LIF_STEPS; ++t) {
        fx4 xt = buf[t & (DEPTH - 1)];       // static index under full unroll
        u = u - o + xt;
        fx4 on;
        on.x = (u.x > LIF_VTH) ? 1.0f : 0.0f;
        on.y = (u.y > LIF_VTH) ? 1.0f : 0.0f;
        on.z = (u.z > LIF_VTH) ? 1.0f : 0.0f;
        on.w = (u.w > LIF_VTH) ? 1.0f : 0.0f;
        o = on;
        __builtin_nontemporal_store(o, &out[(size_t)t * (size_t)n4 + (size_t)i]);
        if (t + DEPTH < LIF_STEPS) {
            buf[t & (DEPTH - 1)] = x[(size_t)(t + DEPTH) * (size_t)n4 + (size_t)i];
        }
    }
}

extern "C" void kernel_launch(void* const* d_in, const int* in_sizes, int n_in,
                              void* d_out, int out_size, void* d_ws, size_t ws_size,
                              hipStream_t stream) {
    const float* x = (const float*)d_in[0];
    float* out = (float*)d_out;

    int total = in_sizes[0];          // T * N
    int n = total / LIF_STEPS;        // spatial elements per timestep
    int n4 = n / 4;                   // float4 elements per timestep

    int block = 256;
    int grid = (n4 + block - 1) / block;

    LIFSpike_84542136254876_kernel<<<grid, block, 0, stream>>>(
        (const fx4*)x, (fx4*)out, n4);
}